// Round 1
// baseline (5776.624 us; speedup 1.0000x reference)
//
#include <hip/hip_runtime.h>
#include <hip/hip_bf16.h>

// FFT-tiled conv: B=8, IMG=256, CIN=COUT=64, TILE=64, FFT=68, PAD=2.
// Frequency-domain per-tile conv via DFT-as-matmul, Hermitian half-spectrum
// (k2 in [0,35)), overlap-add gather. All fp32.

#define FFTN 68
#define KH   35          // half spectrum columns (68/2 + 1)
#define NCH  64          // CIN == COUT
#define TSZ  64          // tile size
#define NTMAX 16

// ---------------- twiddle tables ----------------
// Wf[k][m] = exp(-2pi i k (m+2)/68)           (68 x 64 cplx)  forward, pad folded
// Wi[p][k] = exp(+2pi i p k /68) / 68         (68 x 68 cplx)  inverse col
// Wg[q][k2]= alpha(k2)/68 * exp(+2pi i q k2/68) (68 x 35 cplx) inverse row + sym weights
__global__ void k_twiddle(float* ws) {
    const float TWO_PI = 6.28318530717958647692f;
    int t = threadIdx.x;
    float* Wf = ws;
    for (int e = t; e < 68 * 64; e += 256) {
        int k = e >> 6, m = e & 63;
        int ph = (k * (m + 2)) % 68;
        float a = TWO_PI * (float)ph / 68.0f;
        Wf[2 * e]     = cosf(a);
        Wf[2 * e + 1] = -sinf(a);
    }
    float* Wi = ws + 8704;
    for (int e = t; e < 68 * 68; e += 256) {
        int p = e / 68, k = e % 68;
        int ph = (p * k) % 68;
        float a = TWO_PI * (float)ph / 68.0f;
        Wi[2 * e]     = cosf(a) / 68.0f;
        Wi[2 * e + 1] = sinf(a) / 68.0f;
    }
    float* Wg = ws + 17952;
    for (int e = t; e < 68 * KH; e += 256) {
        int q = e / KH, k2 = e % KH;
        int ph = (q * k2) % 68;
        float a = TWO_PI * (float)ph / 68.0f;
        float alpha = (k2 == 0 || k2 == 34) ? 1.0f : 2.0f;
        Wg[2 * e]     = alpha * cosf(a) / 68.0f;
        Wg[2 * e + 1] = alpha * sinf(a) / 68.0f;
    }
}

__global__ void k_zero(float* out, int n) {
    for (int i = blockIdx.x * 256 + threadIdx.x; i < n; i += gridDim.x * 256)
        out[i] = 0.0f;
}

// ---------------- stage 1: row DFT (over columns c) ----------------
// Y[nl][r][i][k2] = sum_c x[b, tr*64+r, tc*64+c, i] * Wf[k2][c]     (real * cplx)
__global__ void k_fwd_row(const float* __restrict__ x, const float* __restrict__ Wf,
                          float* __restrict__ Y, int s) {
    __shared__ float xr[64 * 64];        // [c][i]
    __shared__ float wf[KH * 64 * 2];    // [k2][c]
    int nl = blockIdx.x >> 6, r = blockIdx.x & 63;
    int n = s + nl;
    int b = n >> 4, tr = (n >> 2) & 3, tc = n & 3;
    const float* src = x + (((size_t)(b * 256 + tr * 64 + r)) * 256 + tc * 64) * 64;
    int t = threadIdx.x;
    for (int e = t; e < 4096; e += 256) xr[e] = src[e];
    for (int e = t; e < KH * 64 * 2; e += 256) wf[e] = Wf[e];
    __syncthreads();
    int i = t & 63, kg = t >> 6;
    float* ybase = Y + (((size_t)nl * 64 + r) * 64 + i) * (2 * KH);
    for (int k2 = kg; k2 < KH; k2 += 4) {
        float ar = 0.f, ai = 0.f;
        const float* w = wf + k2 * 128;
        for (int c = 0; c < 64; ++c) {
            float v = xr[(c << 6) | i];
            ar += v * w[2 * c];
            ai += v * w[2 * c + 1];
        }
        ybase[2 * k2]     = ar;
        ybase[2 * k2 + 1] = ai;
    }
}

// ---------------- stage 2: column DFT ----------------
// X[bin=(k1*KH+k2)][i][nl] = sum_r Wf[k1][r] * Y[nl][r][i][k2]
__global__ void k_fwd_col(const float* __restrict__ Y, const float* __restrict__ Wf,
                          float* __restrict__ X, int NT) {
    __shared__ float yl[64 * KH * 2];    // [r][k2]
    __shared__ float wf[68 * 64 * 2];    // [k1][r]
    int nl = blockIdx.x >> 6, i = blockIdx.x & 63;
    int t = threadIdx.x;
    for (int e = t; e < 64 * KH * 2; e += 256) {
        int r = e / (2 * KH), rem = e % (2 * KH);
        yl[e] = Y[(((size_t)nl * 64 + r) * 64 + i) * (2 * KH) + rem];
    }
    for (int e = t; e < 68 * 64 * 2; e += 256) wf[e] = Wf[e];
    __syncthreads();
    for (int oi = t; oi < 68 * KH; oi += 256) {
        int k1 = oi / KH, k2 = oi % KH;
        float ar = 0.f, ai = 0.f;
        const float* w = wf + k1 * 128;
        const float* yy = yl + k2 * 2;
        for (int r = 0; r < 64; ++r) {
            float br = w[2 * r], bi = w[2 * r + 1];
            float cr = yy[r * 2 * KH], ci = yy[r * 2 * KH + 1];
            ar += br * cr - bi * ci;
            ai += br * ci + bi * cr;
        }
        size_t xi = ((size_t)oi * 64 + i) * NT + nl;
        X[2 * xi]     = ar;
        X[2 * xi + 1] = ai;
    }
}

// ---------------- stage 3: per-bin channel mix ----------------
// O[nl][o][k1][k2] = sum_i X[bin][i][nl] * K[o][i][k1][k2]
__global__ void k_mix(const float* __restrict__ X, const float* __restrict__ kr,
                      const float* __restrict__ ki, float* __restrict__ O, int NT) {
    __shared__ float xl[64 * NTMAX * 2];  // [i][n]
    __shared__ float kl[64 * 64 * 2];     // [i][o]
    int bin = blockIdx.x;                 // k1*KH + k2
    int k1 = bin / KH, k2 = bin % KH;
    int t = threadIdx.x;
    for (int e = t; e < 64 * NT * 2; e += 256) xl[e] = X[(size_t)bin * 64 * NT * 2 + e];
    for (int e = t; e < 4096; e += 256) {
        int o = e >> 6, i = e & 63;
        size_t gi = ((size_t)(o * 64 + i) * 68 + k1) * 68 + k2;
        kl[(i * 64 + o) * 2]     = kr[gi];
        kl[(i * 64 + o) * 2 + 1] = ki[gi];
    }
    __syncthreads();
    int o = t & 63, g = t >> 6;
    for (int n = g; n < NT; n += 4) {
        float ar = 0.f, ai = 0.f;
        for (int i = 0; i < 64; ++i) {
            float br = kl[(i * 64 + o) * 2], bi = kl[(i * 64 + o) * 2 + 1];
            float cr = xl[(i * NT + n) * 2], ci = xl[(i * NT + n) * 2 + 1];
            ar += br * cr - bi * ci;
            ai += br * ci + bi * cr;
        }
        size_t oi = (((size_t)n * 64 + o) * 68 + k1) * KH + k2;
        O[2 * oi]     = ar;
        O[2 * oi + 1] = ai;
    }
}

// ---------------- stage 4: inverse column DFT ----------------
// Z[no][p][k2] = sum_k1 Wi[p][k1] * O[no][k1][k2]
__global__ void k_inv_col(const float* __restrict__ O, const float* __restrict__ Wi,
                          float* __restrict__ Z) {
    __shared__ float ol[68 * KH * 2];    // [k1][k2]
    __shared__ float wi[68 * 68 * 2];    // [p][k1]
    int no = blockIdx.x;                 // nl*64 + o
    int t = threadIdx.x;
    for (int e = t; e < 68 * KH * 2; e += 256) ol[e] = O[(size_t)no * 68 * KH * 2 + e];
    for (int e = t; e < 68 * 68 * 2; e += 256) wi[e] = Wi[e];
    __syncthreads();
    for (int oi = t; oi < 68 * KH; oi += 256) {
        int p = oi / KH, k2 = oi % KH;
        float ar = 0.f, ai = 0.f;
        const float* w = wi + p * 136;
        const float* oo = ol + k2 * 2;
        for (int k1 = 0; k1 < 68; ++k1) {
            float br = w[2 * k1], bi = w[2 * k1 + 1];
            float cr = oo[k1 * 2 * KH], ci = oo[k1 * 2 * KH + 1];
            ar += br * cr - bi * ci;
            ai += br * ci + bi * cr;
        }
        Z[(size_t)no * 68 * KH * 2 + 2 * oi]     = ar;
        Z[(size_t)no * 68 * KH * 2 + 2 * oi + 1] = ai;
    }
}

// ---------------- stage 5: inverse row DFT + overlap-add gather ----------------
// out[b,y,x,o] += sum_{tiles (tr,tc) in chunk} [ bias[o] +
//     sum_{k2} Re( Z[nl][o][y-66tr][k2] * Wg[x-66tc][k2] ) ]
__global__ void k_gather(const float* __restrict__ Z, const float* __restrict__ Wg,
                         const float* __restrict__ bias, float* __restrict__ out,
                         int s, int NT) {
    __shared__ float wg[68 * KH * 2];
    int t = threadIdx.x;
    for (int e = t; e < 68 * KH * 2; e += 256) wg[e] = Wg[e];
    __syncthreads();
    int y = blockIdx.x & 255;
    int b = s >> 4;                      // chunk lies within one batch image
    int o = t & 63, w = t >> 6;
    float bv = bias[o];
    int tr_hi = min(3, y / 66);
    int tr_lo = (y <= 67) ? 0 : (y - 2) / 66;
    for (int xx = 0; xx < 64; ++xx) {
        int x = w * 64 + xx;
        int tc_hi = min(3, x / 66);
        int tc_lo = (x <= 67) ? 0 : (x - 2) / 66;
        float acc = 0.f;
        for (int tr = tr_lo; tr <= tr_hi; ++tr) {
            int p = y - 66 * tr;
            for (int tc = tc_lo; tc <= tc_hi; ++tc) {
                int n = b * 16 + tr * 4 + tc;
                int nl = n - s;
                if (nl < 0 || nl >= NT) continue;
                int q = x - 66 * tc;
                const float* zrow = Z + (((size_t)nl * 64 + o) * 68 + p) * (2 * KH);
                const float* wrow = wg + q * (2 * KH);
                float a = 0.f;
                for (int k2 = 0; k2 < KH; ++k2) {
                    a += zrow[2 * k2] * wrow[2 * k2] - zrow[2 * k2 + 1] * wrow[2 * k2 + 1];
                }
                acc += a + bv;
            }
        }
        size_t oidx = (((size_t)b * 256 + y) * 256 + x) * 64 + o;
        out[oidx] += acc;
    }
}

extern "C" void kernel_launch(void* const* d_in, const int* in_sizes, int n_in,
                              void* d_out, int out_size, void* d_ws, size_t ws_size,
                              hipStream_t stream) {
    const float* x    = (const float*)d_in[0];
    const float* kr   = (const float*)d_in[1];
    const float* ki   = (const float*)d_in[2];
    const float* bias = (const float*)d_in[3];
    float* out = (float*)d_out;
    float* ws  = (float*)d_ws;

    // chunk size (tiles), power-of-two divisor of 16, sized to workspace
    int NT = 16;
    while (NT > 1 && (22720ull + 3ull * (size_t)NT * 304640ull) * 4ull > ws_size) NT >>= 1;

    float* Wf   = ws;                         // 8704 floats
    float* Wi   = ws + 8704;                  // 9248 floats
    float* Wg   = ws + 17952;                 // 4760 floats
    float* bufA = ws + 22720;                 // NT*304640 floats (Y, then Z)
    float* bufB = bufA + (size_t)NT * 304640; // X
    float* bufC = bufB + (size_t)NT * 304640; // O

    k_twiddle<<<1, 256, 0, stream>>>(ws);
    k_zero<<<2048, 256, 0, stream>>>(out, 8 * 256 * 256 * 64);

    for (int s = 0; s < 128; s += NT) {
        k_fwd_row<<<NT * 64, 256, 0, stream>>>(x, Wf, bufA, s);
        k_fwd_col<<<NT * 64, 256, 0, stream>>>(bufA, Wf, bufB, NT);
        k_mix<<<68 * KH, 256, 0, stream>>>(bufB, kr, ki, bufC, NT);
        k_inv_col<<<NT * 64, 256, 0, stream>>>(bufC, Wi, bufA);
        k_gather<<<256, 256, 0, stream>>>(bufA, Wg, bias, out, s, NT);
    }
}

// Round 2
// 4343.469 us; speedup vs baseline: 1.3300x; 1.3300x over previous
//
#include <hip/hip_runtime.h>
#include <hip/hip_bf16.h>

// FFT-tiled conv: B=8, IMG=256, CIN=COUT=64, TILE=64, FFT=68, PAD=2.
// Frequency-domain per-tile conv via DFT-as-matmul, Hermitian half-spectrum
// (k2 in [0,35)), overlap-add gather. All fp32.

#define FFTN 68
#define KH   35          // half spectrum columns (68/2 + 1)
#define NCH  64          // CIN == COUT
#define TSZ  64          // tile size
#define NTMAX 16

// ---------------- twiddle tables ----------------
// Wf[k][m] = exp(-2pi i k (m+2)/68)           (68 x 64 cplx)  forward, pad folded
// Wi[p][k] = exp(+2pi i p k /68) / 68         (68 x 68 cplx)  inverse col
// Wg[q][k2]= alpha(k2)/68 * exp(+2pi i q k2/68) (68 x 35 cplx) inverse row + sym weights
__global__ void k_twiddle(float* ws) {
    const float TWO_PI = 6.28318530717958647692f;
    int t = threadIdx.x;
    float* Wf = ws;
    for (int e = t; e < 68 * 64; e += 256) {
        int k = e >> 6, m = e & 63;
        int ph = (k * (m + 2)) % 68;
        float a = TWO_PI * (float)ph / 68.0f;
        Wf[2 * e]     = cosf(a);
        Wf[2 * e + 1] = -sinf(a);
    }
    float* Wi = ws + 8704;
    for (int e = t; e < 68 * 68; e += 256) {
        int p = e / 68, k = e % 68;
        int ph = (p * k) % 68;
        float a = TWO_PI * (float)ph / 68.0f;
        Wi[2 * e]     = cosf(a) / 68.0f;
        Wi[2 * e + 1] = sinf(a) / 68.0f;
    }
    float* Wg = ws + 17952;
    for (int e = t; e < 68 * KH; e += 256) {
        int q = e / KH, k2 = e % KH;
        int ph = (q * k2) % 68;
        float a = TWO_PI * (float)ph / 68.0f;
        float alpha = (k2 == 0 || k2 == 34) ? 1.0f : 2.0f;
        Wg[2 * e]     = alpha * cosf(a) / 68.0f;
        Wg[2 * e + 1] = alpha * sinf(a) / 68.0f;
    }
}

__global__ void k_zero(float* out, int n) {
    for (int i = blockIdx.x * 256 + threadIdx.x; i < n; i += gridDim.x * 256)
        out[i] = 0.0f;
}

// ---------------- stage 1: row DFT (over columns c) ----------------
// Y[nl][r][i][k2] = sum_c x[b, tr*64+r, tc*64+c, i] * Wf[k2][c]     (real * cplx)
__global__ void k_fwd_row(const float* __restrict__ x, const float* __restrict__ Wf,
                          float* __restrict__ Y, int s) {
    __shared__ float xr[64 * 64];        // [c][i]
    __shared__ float wf[KH * 64 * 2];    // [k2][c]
    int nl = blockIdx.x >> 6, r = blockIdx.x & 63;
    int n = s + nl;
    int b = n >> 4, tr = (n >> 2) & 3, tc = n & 3;
    const float* src = x + (((size_t)(b * 256 + tr * 64 + r)) * 256 + tc * 64) * 64;
    int t = threadIdx.x;
    for (int e = t; e < 4096; e += 256) xr[e] = src[e];
    for (int e = t; e < KH * 64 * 2; e += 256) wf[e] = Wf[e];
    __syncthreads();
    int i = t & 63, kg = t >> 6;
    float* ybase = Y + (((size_t)nl * 64 + r) * 64 + i) * (2 * KH);
    for (int k2 = kg; k2 < KH; k2 += 4) {
        float ar = 0.f, ai = 0.f;
        const float* w = wf + k2 * 128;
        for (int c = 0; c < 64; ++c) {
            float v = xr[(c << 6) | i];
            ar += v * w[2 * c];
            ai += v * w[2 * c + 1];
        }
        ybase[2 * k2]     = ar;
        ybase[2 * k2 + 1] = ai;
    }
}

// ---------------- stage 2: column DFT ----------------
// X[bin=(k1*KH+k2)][i][nl] = sum_r Wf[k1][r] * Y[nl][r][i][k2]
__global__ void k_fwd_col(const float* __restrict__ Y, const float* __restrict__ Wf,
                          float* __restrict__ X, int NT) {
    __shared__ float yl[64 * KH * 2];    // [r][k2]
    __shared__ float wf[68 * 64 * 2];    // [k1][r]
    int nl = blockIdx.x >> 6, i = blockIdx.x & 63;
    int t = threadIdx.x;
    for (int e = t; e < 64 * KH * 2; e += 256) {
        int r = e / (2 * KH), rem = e % (2 * KH);
        yl[e] = Y[(((size_t)nl * 64 + r) * 64 + i) * (2 * KH) + rem];
    }
    for (int e = t; e < 68 * 64 * 2; e += 256) wf[e] = Wf[e];
    __syncthreads();
    for (int oi = t; oi < 68 * KH; oi += 256) {
        int k1 = oi / KH, k2 = oi % KH;
        float ar = 0.f, ai = 0.f;
        const float* w = wf + k1 * 128;
        const float* yy = yl + k2 * 2;
        for (int r = 0; r < 64; ++r) {
            float br = w[2 * r], bi = w[2 * r + 1];
            float cr = yy[r * 2 * KH], ci = yy[r * 2 * KH + 1];
            ar += br * cr - bi * ci;
            ai += br * ci + bi * cr;
        }
        size_t xi = ((size_t)oi * 64 + i) * NT + nl;
        X[2 * xi]     = ar;
        X[2 * xi + 1] = ai;
    }
}

// ---------------- stage 3: per-bin channel mix ----------------
// O[nl][o][k1][k2] = sum_i X[bin][i][nl] * K[o][i][k1][k2]
__global__ void k_mix(const float* __restrict__ X, const float* __restrict__ kr,
                      const float* __restrict__ ki, float* __restrict__ O, int NT) {
    __shared__ float xl[64 * NTMAX * 2];  // [i][n]
    __shared__ float kl[64 * 64 * 2];     // [i][o]
    int bin = blockIdx.x;                 // k1*KH + k2
    int k1 = bin / KH, k2 = bin % KH;
    int t = threadIdx.x;
    for (int e = t; e < 64 * NT * 2; e += 256) xl[e] = X[(size_t)bin * 64 * NT * 2 + e];
    for (int e = t; e < 4096; e += 256) {
        int o = e >> 6, i = e & 63;
        size_t gi = ((size_t)(o * 64 + i) * 68 + k1) * 68 + k2;
        kl[(i * 64 + o) * 2]     = kr[gi];
        kl[(i * 64 + o) * 2 + 1] = ki[gi];
    }
    __syncthreads();
    int o = t & 63, g = t >> 6;
    for (int n = g; n < NT; n += 4) {
        float ar = 0.f, ai = 0.f;
        for (int i = 0; i < 64; ++i) {
            float br = kl[(i * 64 + o) * 2], bi = kl[(i * 64 + o) * 2 + 1];
            float cr = xl[(i * NT + n) * 2], ci = xl[(i * NT + n) * 2 + 1];
            ar += br * cr - bi * ci;
            ai += br * ci + bi * cr;
        }
        size_t oi = (((size_t)n * 64 + o) * 68 + k1) * KH + k2;
        O[2 * oi]     = ar;
        O[2 * oi + 1] = ai;
    }
}

// ---------------- stage 4: inverse column DFT ----------------
// Z[no][p][k2] = sum_k1 Wi[p][k1] * O[no][k1][k2]
__global__ void k_inv_col(const float* __restrict__ O, const float* __restrict__ Wi,
                          float* __restrict__ Z) {
    __shared__ float ol[68 * KH * 2];    // [k1][k2]
    __shared__ float wi[68 * 68 * 2];    // [p][k1]
    int no = blockIdx.x;                 // nl*64 + o
    int t = threadIdx.x;
    for (int e = t; e < 68 * KH * 2; e += 256) ol[e] = O[(size_t)no * 68 * KH * 2 + e];
    for (int e = t; e < 68 * 68 * 2; e += 256) wi[e] = Wi[e];
    __syncthreads();
    for (int oi = t; oi < 68 * KH; oi += 256) {
        int p = oi / KH, k2 = oi % KH;
        float ar = 0.f, ai = 0.f;
        const float* w = wi + p * 136;
        const float* oo = ol + k2 * 2;
        for (int k1 = 0; k1 < 68; ++k1) {
            float br = w[2 * k1], bi = w[2 * k1 + 1];
            float cr = oo[k1 * 2 * KH], ci = oo[k1 * 2 * KH + 1];
            ar += br * cr - bi * ci;
            ai += br * ci + bi * cr;
        }
        Z[(size_t)no * 68 * KH * 2 + 2 * oi]     = ar;
        Z[(size_t)no * 68 * KH * 2 + 2 * oi + 1] = ai;
    }
}

// ---------------- stage 5a: inverse row DFT per tile-row ----------------
// S[nl][p][q][o] = sum_k2 Re( Z[nl][o][p][k2] * Wg[q][k2] )
__global__ void k_inv_row(const float* __restrict__ Z, const float* __restrict__ Wg,
                          float* __restrict__ S) {
    __shared__ float zl[64 * 71];        // [o][2*KH] padded to 71 (bank-conflict-free)
    __shared__ float wgs[68 * 70];       // [q][2*KH]
    int nl = blockIdx.x / 68, p = blockIdx.x % 68;
    int t = threadIdx.x;
    for (int e = t; e < 64 * 70; e += 256) {
        int o = e / 70, rem = e % 70;
        zl[o * 71 + rem] = Z[(((size_t)(nl * 64 + o)) * 68 + p) * 70 + rem];
    }
    for (int e = t; e < 68 * 70; e += 256) wgs[e] = Wg[e];
    __syncthreads();
    int o = t & 63, g = t >> 6;
    const float* zr = zl + o * 71;
    float* sbase = S + ((size_t)nl * 68 + p) * 68 * 64 + o;
    for (int q = g; q < 68; q += 4) {
        const float* w = wgs + q * 70;
        float acc = 0.f;
        for (int k2 = 0; k2 < KH; ++k2) {
            acc = fmaf(zr[2 * k2], w[2 * k2], acc);
            acc = fmaf(-zr[2 * k2 + 1], w[2 * k2 + 1], acc);
        }
        sbase[(size_t)q * 64] = acc;
    }
}

// ---------------- stage 5b: overlap-add gather (memory-bound) ----------------
// out[b,y,x,o] (+)= sum_{tiles (tr,tc)} S[nl][y-66tr][x-66tc][o] + bias[o]
__global__ void k_oadd(const float* __restrict__ S, const float* __restrict__ bias,
                       float* __restrict__ out, int s, int NT, int store_mode) {
    int y = blockIdx.x >> 2, xq = blockIdx.x & 3;
    int b = s >> 4;                      // chunk lies within one batch image
    int t = threadIdx.x;
    int o = t & 63, xg = t >> 6;
    float bv = bias[o];
    int tr_hi = min(3, y / 66);
    int tr_lo = (y <= 67) ? 0 : (y - 2) / 66;
    for (int xx = 0; xx < 16; ++xx) {
        int x = xq * 64 + xg * 16 + xx;
        int tc_hi = min(3, x / 66);
        int tc_lo = (x <= 67) ? 0 : (x - 2) / 66;
        float acc = 0.f;
        for (int tr = tr_lo; tr <= tr_hi; ++tr) {
            int p = y - 66 * tr;
            for (int tc = tc_lo; tc <= tc_hi; ++tc) {
                int n = b * 16 + tr * 4 + tc;
                int nl = n - s;
                if (nl < 0 || nl >= NT) continue;
                int q = x - 66 * tc;
                acc += S[((((size_t)nl * 68 + p) * 68) + q) * 64 + o] + bv;
            }
        }
        size_t oidx = (((size_t)b * 256 + y) * 256 + x) * 64 + o;
        if (store_mode) out[oidx] = acc;
        else            out[oidx] += acc;
    }
}

extern "C" void kernel_launch(void* const* d_in, const int* in_sizes, int n_in,
                              void* d_out, int out_size, void* d_ws, size_t ws_size,
                              hipStream_t stream) {
    const float* x    = (const float*)d_in[0];
    const float* kr   = (const float*)d_in[1];
    const float* ki   = (const float*)d_in[2];
    const float* bias = (const float*)d_in[3];
    float* out = (float*)d_out;
    float* ws  = (float*)d_ws;

    // chunk size (tiles), power-of-two divisor of 16, sized to workspace
    int NT = 16;
    while (NT > 1 && (22720ull + 3ull * (size_t)NT * 304640ull) * 4ull > ws_size) NT >>= 1;

    float* Wf   = ws;                         // 8704 floats
    float* Wi   = ws + 8704;                  // 9248 floats
    float* Wg   = ws + 17952;                 // 4760 floats
    float* bufA = ws + 22720;                 // NT*304640 floats (Y, then Z)
    float* bufB = bufA + (size_t)NT * 304640; // X, then S (NT*68*68*64 <= NT*304640)
    float* bufC = bufB + (size_t)NT * 304640; // O

    k_twiddle<<<1, 256, 0, stream>>>(ws);
    int store_mode = (NT == 16) ? 1 : 0;
    if (!store_mode)
        k_zero<<<2048, 256, 0, stream>>>(out, 8 * 256 * 256 * 64);

    for (int s = 0; s < 128; s += NT) {
        k_fwd_row<<<NT * 64, 256, 0, stream>>>(x, Wf, bufA, s);
        k_fwd_col<<<NT * 64, 256, 0, stream>>>(bufA, Wf, bufB, NT);
        k_mix<<<68 * KH, 256, 0, stream>>>(bufB, kr, ki, bufC, NT);
        k_inv_col<<<NT * 64, 256, 0, stream>>>(bufC, Wi, bufA);
        k_inv_row<<<NT * 68, 256, 0, stream>>>(bufA, Wg, bufB);
        k_oadd<<<256 * 4, 256, 0, stream>>>(bufB, bias, out, s, NT, store_mode);
    }
}